// Round 14
// baseline (377.341 us; speedup 1.0000x reference)
//
#include <hip/hip_runtime.h>
#include <hip/hip_bf16.h>

typedef unsigned short u16;
typedef __attribute__((ext_vector_type(8))) __bf16 bf16x8;
typedef __attribute__((ext_vector_type(4))) float f32x4;
typedef __attribute__((ext_vector_type(4))) unsigned short u16x4;

#define DEVI static __device__ __forceinline__

// round-to-nearest-even f32 -> bf16 bits
DEVI u16 f2bf(float f) {
    union { float f; unsigned u; } v; v.f = f;
    unsigned r = v.u + 0x7fffu + ((v.u >> 16) & 1u);
    return (u16)(r >> 16);
}

DEVI unsigned cvt_pk_bf16(float lo, float hi) {
    unsigned r;
    asm("v_cvt_pk_bf16_f32 %0, %1, %2" : "=v"(r) : "v"(lo), "v"(hi));
    return r;
}

DEVI void gload16(const u16* g, u16* l) {
    __builtin_amdgcn_global_load_lds(
        (const __attribute__((address_space(1))) void*)g,
        (__attribute__((address_space(3))) void*)l, 16, 0, 0);
}

// ---------------- prep kernels ----------------

__global__ void k_cast_scale(const float* __restrict__ src, u16* __restrict__ dst,
                             int n, float scale) {
    int i = (blockIdx.x * blockDim.x + threadIdx.x) * 4;
    if (i >= n) return;
    float4 v = *(const float4*)(src + i);
    u16x4 o = { f2bf(v.x * scale), f2bf(v.y * scale), f2bf(v.z * scale), f2bf(v.w * scale) };
    *(u16x4*)(dst + i) = o;
}

// W[o][i][t] f32 -> Wt[t][o][i] bf16 (1024x1024x7); blockIdx.y selects K/V
__global__ void k_castW2(const float* __restrict__ wk, const float* __restrict__ wv,
                         u16* __restrict__ wtk, u16* __restrict__ wtv) {
    int oi = blockIdx.x * blockDim.x + threadIdx.x;
    const float* p = (blockIdx.y ? wv : wk) + (size_t)oi * 7;
    u16* wt = blockIdx.y ? wtv : wtk;
#pragma unroll
    for (int t = 0; t < 7; ++t)
        wt[(size_t)t * 1048576 + oi] = f2bf(p[t]);
}

// x[b][i=1024][l=512] f32 -> out[b][l+6][i] bf16; blocks at l0==0 also zero
// the 6 causal pad rows. blockIdx.z: 0..15 = key batch z, 16..31 = value z-16.
__global__ void k_transpose_pad2(const float* __restrict__ xk, const float* __restrict__ xv,
                                 u16* __restrict__ ok, u16* __restrict__ ov) {
    __shared__ float tile[64][65];
    int z = blockIdx.z;
    bool isV = z >= 16;
    int b = isV ? z - 16 : z;
    const float* x = isV ? xv : xk;
    u16* out = isV ? ov : ok;
    int l0 = blockIdx.x * 64, i0 = blockIdx.y * 64;
    int t = threadIdx.x;
    const float* xb = x + (size_t)b * 1024 * 512;
    u16* ob = out + (size_t)b * 520 * 1024;
    if (blockIdx.x == 0 && t < 96) {   // zero pad rows 0..5, cols i0..i0+63
        int pr = t >> 4, pc = (t & 15) * 4;
        u16x4 zz = { 0, 0, 0, 0 };
        *(u16x4*)(ob + (size_t)pr * 1024 + i0 + pc) = zz;
    }
    int tr = t >> 4, tc = (t & 15) * 4;
#pragma unroll
    for (int r = 0; r < 4; ++r) {
        int row = tr + r * 16;
        float4 v = *(const float4*)(xb + (size_t)(i0 + row) * 512 + l0 + tc);
        tile[row][tc + 0] = v.x; tile[row][tc + 1] = v.y;
        tile[row][tc + 2] = v.z; tile[row][tc + 3] = v.w;
    }
    __syncthreads();
#pragma unroll
    for (int r = 0; r < 4; ++r) {
        int lr = tr + r * 16;
        u16x4 o = { f2bf(tile[tc + 0][lr]), f2bf(tile[tc + 1][lr]),
                    f2bf(tile[tc + 2][lr]), f2bf(tile[tc + 3][lr]) };
        *(u16x4*)(ob + (size_t)(l0 + 6 + lr) * 1024 + i0 + tc) = o;
    }
}

// ---------------- dual-conv GEMM: A from L2 to regs, B-only LDS ----------------
// Y[b][o][l] = sum_t sum_i Wt[t][o][i] * Xt[b][l+t][i] + bias[o]
// 512 blocks, 256 thr = 4 waves (2M x 2N), BM=128 (o), BN=256 (l), BK=64.
// id&7 -> o-tile (XCD-pinned weight panel, hot in that XCD's 4MB L2);
// (id>>3)&1 -> conv; id>>4 -> (b, l-tile).
// CHANGE vs r10/r13 (based on r13 counters: LDS-unit 107us ~= MFMA 100us,
// co-critical): A-frags are loaded DIRECTLY from global(L2) into VGPRs
// (compiler-scheduled/prefetched across the unrolled tap loop) -> LDS reads
// drop 24->16 per wave-step (107->71us), stageA + per-tap barrier/drain pairs
// vanish (112 -> 16 barrier boundaries; waves drift freely across taps =
// m97-style implicit overlap). LDS: B slab only, dbuf 2x[264][64] = 66KB ->
// 2 blocks/CU. Counted protocol per ic: {stage(ic+1,slot^1) at top; 7 taps
// of A-gload + B-ds_read + 64 MFMA; barrier; vmcnt(0); barrier}.
// T2 XOR swizzle on B. No setprio, no SGB (proven harmful r8/r9).
__global__ __launch_bounds__(256, 2)
void k_conv128g(const u16* __restrict__ WtK, const u16* __restrict__ WtV,
                const u16* __restrict__ XtK, const u16* __restrict__ XtV,
                const float* __restrict__ bK, const float* __restrict__ bV,
                u16* __restrict__ YK, u16* __restrict__ YV) {
    __shared__ __align__(16) u16 Bs[2][16896];   // 2 x [264][64]
    int id = blockIdx.x;
    int o0 = (id & 7) * 128;
    bool isV = (id >> 3) & 1;
    int inner = id >> 4;                 // 0..31
    int b = inner & 15;
    int l0 = (inner >> 4) * 256;
    const u16* Wt = isV ? WtV : WtK;
    const u16* Xb = (isV ? XtV : XtK) + (size_t)b * 520 * 1024;
    int tid = threadIdx.x, lane = tid & 63, wave = tid >> 6;
    int q = lane & 15, g = lane >> 4;
    int wm = wave >> 1, wn = wave & 1;

    // per-wave A base: row (o0 + wm*64 + mf*16 + q), col (kk*4+g)*8
    const u16* Aw = Wt + (size_t)(o0 + wm * 64 + q) * 1024 + g * 8;

    int sr = tid >> 3;                   // 0..31
    int ss = (tid & 7) ^ (sr & 7);

    auto stageB = [&](int ic, int slot) {
        const u16* bb = Xb + (size_t)(l0 + sr) * 1024 + (ic << 6) + ss * 8;
        u16* bd = &Bs[slot][tid * 8];
#pragma unroll
        for (int l = 0; l < 8; ++l)
            gload16(bb + (size_t)(l << 5) * 1024, bd + (l << 11));
        int sr5 = 256 + (sr & 7);        // sr5&7 == sr&7 -> same ss key
        gload16(Xb + (size_t)(l0 + sr5) * 1024 + (ic << 6) + ss * 8,
                &Bs[slot][sr5 * 64 + (tid & 7) * 8]);
    };

    f32x4 acc[4][8] = {};

    stageB(0, 0);
    asm volatile("s_waitcnt vmcnt(0)" ::: "memory");
    __builtin_amdgcn_s_barrier();

    for (int ic = 0; ic < 16; ++ic) {
        int slot = ic & 1;
        if (ic + 1 < 16) stageB(ic + 1, slot ^ 1);   // prefetch, lands under 7 taps
        const u16* Bsl = Bs[slot];
        const u16* Aic = Aw + (ic << 6);
#pragma unroll
        for (int t = 0; t < 7; ++t) {
            const u16* At = Aic + ((size_t)t << 20);
            bf16x8 af[4][2], bfr[4][2];
            // A frags from global (L2-resident panel) -> registers
#pragma unroll
            for (int mf = 0; mf < 4; ++mf)
#pragma unroll
                for (int kk = 0; kk < 2; ++kk)
                    af[mf][kk] = *(const bf16x8*)(At + mf * 16384 + kk * 32);
            // B frags nf 0..3 from LDS (swizzled); 32 MFMA
#pragma unroll
            for (int nf = 0; nf < 4; ++nf) {
                int r = wn * 128 + nf * 16 + q + t;
                const u16* base = Bsl + r * 64;
#pragma unroll
                for (int kk = 0; kk < 2; ++kk)
                    bfr[nf][kk] = *(const bf16x8*)(base + (((kk * 4 + g) ^ (r & 7)) << 3));
            }
#pragma unroll
            for (int mf = 0; mf < 4; ++mf)
#pragma unroll
                for (int nf = 0; nf < 4; ++nf)
#pragma unroll
                    for (int kk = 0; kk < 2; ++kk)
                        acc[mf][nf] = __builtin_amdgcn_mfma_f32_16x16x32_bf16(
                            af[mf][kk], bfr[nf][kk], acc[mf][nf], 0, 0, 0);
            // B frags nf 4..7; 32 MFMA
#pragma unroll
            for (int nf = 0; nf < 4; ++nf) {
                int r = wn * 128 + (4 + nf) * 16 + q + t;
                const u16* base = Bsl + r * 64;
#pragma unroll
                for (int kk = 0; kk < 2; ++kk)
                    bfr[nf][kk] = *(const bf16x8*)(base + (((kk * 4 + g) ^ (r & 7)) << 3));
            }
#pragma unroll
            for (int mf = 0; mf < 4; ++mf)
#pragma unroll
                for (int nf = 0; nf < 4; ++nf)
#pragma unroll
                    for (int kk = 0; kk < 2; ++kk)
                        acc[mf][4 + nf] = __builtin_amdgcn_mfma_f32_16x16x32_bf16(
                            af[mf][kk], bfr[nf][kk], acc[mf][4 + nf], 0, 0, 0);
        }
        // ic boundary: all waves done reading slot; B(ic+1) landed; visible.
        asm volatile("" ::: "memory");
        __builtin_amdgcn_s_barrier();
        asm volatile("s_waitcnt vmcnt(0)" ::: "memory");
        __builtin_amdgcn_s_barrier();
    }

    const float* bias = isV ? bV : bK;
#pragma unroll
    for (int mf = 0; mf < 4; ++mf) {
        int ro = o0 + wm * 64 + mf * 16 + g * 4;
        float b0 = bias[ro + 0], b1 = bias[ro + 1], b2 = bias[ro + 2], b3 = bias[ro + 3];
#pragma unroll
        for (int nf = 0; nf < 8; ++nf) {
            int co = l0 + wn * 128 + nf * 16 + q;
            f32x4 a = acc[mf][nf];
            if (isV) {
                u16x4 o = { f2bf(a[0] + b0), f2bf(a[1] + b1), f2bf(a[2] + b2), f2bf(a[3] + b3) };
                *(u16x4*)&YV[((size_t)b * 512 + co) * 1024 + ro] = o;
            } else {
                u16* yp = &YK[((size_t)b * 1024 + ro) * 512 + co];
                yp[0]    = f2bf(a[0] + b0);
                yp[512]  = f2bf(a[1] + b1);
                yp[1024] = f2bf(a[2] + b2);
                yp[1536] = f2bf(a[3] + b3);
            }
        }
    }
}

// ---------------- fused attention (unchanged) ----------------
__global__ __launch_bounds__(512, 4)
void k_attn2(const u16* __restrict__ Q, const u16* __restrict__ K,
             const u16* __restrict__ Vt, u16* __restrict__ O) {
    __shared__ __align__(16) u16 Ks[2][64 * 64];
    __shared__ __align__(16) u16 Vs[2][64 * 64];
    int b = blockIdx.z, h = blockIdx.y, q0 = blockIdx.x * 128;
    int tid = threadIdx.x, lane = tid & 63, wave = tid >> 6;
    int g = lane >> 4, q = lane & 15;

    const u16* Kb = K + (size_t)b * 1024 * 512 + h * 64;
    const u16* Vb = Vt + ((size_t)b * 512 + h * 64) * 1024;
    const u16* Qb = Q + ((size_t)b * 1024 + q0 + wave * 16 + q) * 512 + h * 64;

    bf16x8 qf[2];
    qf[0] = *(const bf16x8*)(Qb + g * 8);
    qf[1] = *(const bf16x8*)(Qb + 32 + g * 8);

    int sr = tid >> 3;
    int ss = (tid & 7) ^ (sr & 7);
    const u16* ksrc = Kb + (size_t)sr * 512 + ss * 8;
    const u16* vsrc = Vb + (size_t)sr * 1024 + ss * 8;

    f32x4 o[4] = {};
    float lsum = 0.f;

    gload16(ksrc, &Ks[0][tid * 8]);
    gload16(vsrc, &Vs[0][tid * 8]);
    __syncthreads();

#pragma unroll 2
    for (int t = 0; t < 16; ++t) {
        int buf = t & 1;
        if (t < 15) {
            gload16(ksrc + (size_t)(t + 1) * 64 * 512, &Ks[buf ^ 1][tid * 8]);
            gload16(vsrc + (t + 1) * 64, &Vs[buf ^ 1][tid * 8]);
        }
        f32x4 s[4];
#pragma unroll
        for (int mf = 0; mf < 4; ++mf) {
            int r = 16 * mf + q;
            const u16* base = &Ks[buf][r * 64];
            bf16x8 kf0 = *(const bf16x8*)(base + (((g) ^ (q & 7)) << 3));
            bf16x8 kf1 = *(const bf16x8*)(base + (((4 + g) ^ (q & 7)) << 3));
            f32x4 zz = {};
            zz = __builtin_amdgcn_mfma_f32_16x16x32_bf16(kf0, qf[0], zz, 0, 0, 0);
            s[mf] = __builtin_amdgcn_mfma_f32_16x16x32_bf16(kf1, qf[1], zz, 0, 0, 0);
        }
        unsigned w[4][2];
#pragma unroll
        for (int mf = 0; mf < 4; ++mf) {
            f32x4 p;
#pragma unroll
            for (int j = 0; j < 4; ++j) {
                p[j] = exp2f(s[mf][j]);
                lsum += p[j];
            }
            w[mf][0] = cvt_pk_bf16(p[0], p[1]);
            w[mf][1] = cvt_pk_bf16(p[2], p[3]);
        }
        bool hi = lane >= 32;
        int ia = ((g & 1) << 5) + q;
        int ib = ia + 16;
#pragma unroll
        for (int c = 0; c < 2; ++c) {
            unsigned a0 = __shfl(w[2 * c][0], ia), b0 = __shfl(w[2 * c + 1][0], ia);
            unsigned a1 = __shfl(w[2 * c][1], ia), b1 = __shfl(w[2 * c + 1][1], ia);
            unsigned a2 = __shfl(w[2 * c][0], ib), b2 = __shfl(w[2 * c + 1][0], ib);
            unsigned a3 = __shfl(w[2 * c][1], ib), b3 = __shfl(w[2 * c + 1][1], ib);
            union { unsigned u[4]; bf16x8 v8; } pu;
            pu.u[0] = hi ? b0 : a0;
            pu.u[1] = hi ? b1 : a1;
            pu.u[2] = hi ? b2 : a2;
            pu.u[3] = hi ? b3 : a3;
            bf16x8 pb = pu.v8;
#pragma unroll
            for (int df = 0; df < 4; ++df) {
                int rd = 16 * df + q;
                bf16x8 vf = *(const bf16x8*)(&Vs[buf][rd * 64] + (((c * 4 + g) ^ (q & 7)) << 3));
                o[df] = __builtin_amdgcn_mfma_f32_16x16x32_bf16(vf, pb, o[df], 0, 0, 0);
            }
        }
        __syncthreads();
    }

    lsum += __shfl_xor(lsum, 16);
    lsum += __shfl_xor(lsum, 32);
    float inv = 1.0f / lsum;

    unsigned wo[4][2];
#pragma unroll
    for (int df = 0; df < 4; ++df) {
        f32x4 v = o[df];
        v[0] *= inv; v[1] *= inv; v[2] *= inv; v[3] *= inv;
        wo[df][0] = cvt_pk_bf16(v[0], v[1]);
        wo[df][1] = cvt_pk_bf16(v[2], v[3]);
    }
    bool hi = lane >= 32;
    int ia = ((g & 1) << 5) + q;
    int ib = ia + 16;
    u16* Ob = O + ((size_t)b * 1024 + q0 + wave * 16 + q) * 512 + h * 64;
#pragma unroll
    for (int c = 0; c < 2; ++c) {
        unsigned a0 = __shfl(wo[2 * c][0], ia), b0 = __shfl(wo[2 * c + 1][0], ia);
        unsigned a1 = __shfl(wo[2 * c][1], ia), b1 = __shfl(wo[2 * c + 1][1], ia);
        unsigned a2 = __shfl(wo[2 * c][0], ib), b2 = __shfl(wo[2 * c + 1][0], ib);
        unsigned a3 = __shfl(wo[2 * c][1], ib), b3 = __shfl(wo[2 * c + 1][1], ib);
        int4 st;
        st.x = (int)(hi ? b0 : a0);
        st.y = (int)(hi ? b1 : a1);
        st.z = (int)(hi ? b2 : a2);
        st.w = (int)(hi ? b3 : a3);
        *(int4*)(Ob + c * 32 + g * 8) = st;
    }
}

// ---------------- output linear ----------------
__global__ __launch_bounds__(256, 2)
void k_gemm_out(const u16* __restrict__ A, const u16* __restrict__ Bt,
                const float* __restrict__ bias, float* __restrict__ C) {
    __shared__ __align__(16) u16 As[128 * 64];
    __shared__ __align__(16) u16 Bs[128 * 64];
    int n0 = blockIdx.x * 128, m0 = blockIdx.y * 128;
    int tid = threadIdx.x, lane = tid & 63, wave = tid >> 6;
    int wr = (wave >> 1) * 64, wc = (wave & 1) * 64;
    f32x4 acc[4][4] = {};

    for (int kk = 0; kk < 8; ++kk) {
        int i0 = kk * 64;
        const u16* asrc = A + (size_t)(m0 + (tid >> 3)) * 512 + i0 + (tid & 7) * 8;
        const u16* bsrc = Bt + (size_t)(n0 + (tid >> 3)) * 512 + i0 + (tid & 7) * 8;
        __syncthreads();
#pragma unroll
        for (int s = 0; s < 4; ++s) {
            gload16(asrc + (size_t)s * 32 * 512, &As[s * 2048 + tid * 8]);
            gload16(bsrc + (size_t)s * 32 * 512, &Bs[s * 2048 + tid * 8]);
        }
        __syncthreads();
#pragma unroll
        for (int ks = 0; ks < 2; ++ks) {
            bf16x8 af[4], bfr[4];
#pragma unroll
            for (int m = 0; m < 4; ++m)
                af[m] = *(const bf16x8*)&As[(wr + m * 16 + (lane & 15)) * 64 + ks * 32 + (lane >> 4) * 8];
#pragma unroll
            for (int n = 0; n < 4; ++n)
                bfr[n] = *(const bf16x8*)&Bs[(wc + n * 16 + (lane & 15)) * 64 + ks * 32 + (lane >> 4) * 8];
#pragma unroll
            for (int m = 0; m < 4; ++m)
#pragma unroll
                for (int n = 0; n < 4; ++n)
                    acc[m][n] = __builtin_amdgcn_mfma_f32_16x16x32_bf16(af[m], bfr[n], acc[m][n], 0, 0, 0);
        }
    }

#pragma unroll
    for (int m = 0; m < 4; ++m) {
        int ro = m0 + wr + m * 16 + (lane >> 4) * 4;
#pragma unroll
        for (int n = 0; n < 4; ++n) {
            int co = n0 + wc + n * 16 + (lane & 15);
            float bb = bias[co];
            float* cp = &C[(size_t)ro * 512 + co];
            cp[0]    = acc[m][n][0] + bb;
            cp[512]  = acc[m][n][1] + bb;
            cp[1024] = acc[m][n][2] + bb;
            cp[1536] = acc[m][n][3] + bb;
        }
    }
}

// ---------------- launcher ----------------
extern "C" void kernel_launch(void* const* d_in, const int* in_sizes, int n_in,
                              void* d_out, int out_size, void* d_ws, size_t ws_size,
                              hipStream_t stream) {
    (void)in_sizes; (void)n_in; (void)out_size; (void)ws_size;
    const float* query = (const float*)d_in[0];
    const float* key   = (const float*)d_in[1];
    const float* value = (const float*)d_in[2];
    const float* wk    = (const float*)d_in[3];
    const float* bk    = (const float*)d_in[4];
    const float* wv    = (const float*)d_in[5];
    const float* bv    = (const float*)d_in[6];
    const float* lw    = (const float*)d_in[7];
    const float* lb    = (const float*)d_in[8];
    float* out = (float*)d_out;

    u16* ws16  = (u16*)d_ws;
    u16* q_bf  = ws16;                  // [16][1024][512]  q * (1/8)*log2e
    u16* k_att = q_bf  + 8388608;       // [16][1024][512]  conv-K out
    u16* v_t   = k_att + 8388608;       // [16][512][1024]  conv-V out (transposed)
    u16* x_att = v_t   + 8388608;       // [16][1024][512]  attention out
    u16* xt_k  = x_att + 8388608;       // [16][520][1024]  key transposed+padded
    u16* xt_v  = xt_k  + 8519680;       // [16][520][1024]
    u16* wk_bf = xt_v  + 8519680;       // [7][1024][1024]
    u16* wv_bf = wk_bf + 7340032;       // [7][1024][1024]
    u16* lw_bf = wv_bf + 7340032;       // [512][512]

    k_cast_scale<<<8192, 256, 0, stream>>>(query, q_bf, 8388608, 0.125f * 1.44269504f);
    k_cast_scale<<<256, 256, 0, stream>>>(lw, lw_bf, 262144, 1.0f);
    k_castW2<<<dim3(4096, 2), 256, 0, stream>>>(wk, wv, wk_bf, wv_bf);
    k_transpose_pad2<<<dim3(8, 16, 32), 256, 0, stream>>>(key, value, xt_k, xt_v);

    k_conv128g<<<dim3(512, 1, 1), 256, 0, stream>>>(wk_bf, wv_bf, xt_k, xt_v, bk, bv, k_att, v_t);

    k_attn2<<<dim3(8, 8, 16), 512, 0, stream>>>(q_bf, k_att, v_t, x_att);

    k_gemm_out<<<dim3(4, 128), 256, 0, stream>>>(x_att, lw_bf, lb, out);
}

// Round 15
// 312.913 us; speedup vs baseline: 1.2059x; 1.2059x over previous
//
#include <hip/hip_runtime.h>
#include <hip/hip_bf16.h>

typedef unsigned short u16;
typedef __attribute__((ext_vector_type(8))) __bf16 bf16x8;
typedef __attribute__((ext_vector_type(4))) float f32x4;
typedef __attribute__((ext_vector_type(4))) unsigned short u16x4;

#define DEVI static __device__ __forceinline__

// round-to-nearest-even f32 -> bf16 bits
DEVI u16 f2bf(float f) {
    union { float f; unsigned u; } v; v.f = f;
    unsigned r = v.u + 0x7fffu + ((v.u >> 16) & 1u);
    return (u16)(r >> 16);
}

DEVI unsigned cvt_pk_bf16(float lo, float hi) {
    unsigned r;
    asm("v_cvt_pk_bf16_f32 %0, %1, %2" : "=v"(r) : "v"(lo), "v"(hi));
    return r;
}

DEVI void gload16(const u16* g, u16* l) {
    __builtin_amdgcn_global_load_lds(
        (const __attribute__((address_space(1))) void*)g,
        (__attribute__((address_space(3))) void*)l, 16, 0, 0);
}

// ---------------- prep kernels ----------------

// merged cast: blocks [0,8192) cast q (scale = 1/8*log2e), blocks [8192,8448) cast lw
__global__ void k_cast_both(const float* __restrict__ q, u16* __restrict__ qd,
                            const float* __restrict__ w, u16* __restrict__ wd) {
    int bid = blockIdx.x;
    if (bid < 8192) {
        int i = (bid * 256 + threadIdx.x) * 4;
        float4 v = *(const float4*)(q + i);
        const float s = 0.125f * 1.44269504f;
        u16x4 o = { f2bf(v.x * s), f2bf(v.y * s), f2bf(v.z * s), f2bf(v.w * s) };
        *(u16x4*)(qd + i) = o;
    } else {
        int i = ((bid - 8192) * 256 + threadIdx.x) * 4;
        float4 v = *(const float4*)(w + i);
        u16x4 o = { f2bf(v.x), f2bf(v.y), f2bf(v.z), f2bf(v.w) };
        *(u16x4*)(wd + i) = o;
    }
}

// W[o][i][t] f32 -> Wt[t][o][i] bf16 (1024x1024x7); blockIdx.y selects K/V
__global__ void k_castW2(const float* __restrict__ wk, const float* __restrict__ wv,
                         u16* __restrict__ wtk, u16* __restrict__ wtv) {
    int oi = blockIdx.x * blockDim.x + threadIdx.x;
    const float* p = (blockIdx.y ? wv : wk) + (size_t)oi * 7;
    u16* wt = blockIdx.y ? wtv : wtk;
#pragma unroll
    for (int t = 0; t < 7; ++t)
        wt[(size_t)t * 1048576 + oi] = f2bf(p[t]);
}

// x[b][i=1024][l=512] f32 -> out[b][l+6][i] bf16; blocks at l0==0 also zero
// the 6 causal pad rows. blockIdx.z: 0..15 = key batch z, 16..31 = value z-16.
__global__ void k_transpose_pad2(const float* __restrict__ xk, const float* __restrict__ xv,
                                 u16* __restrict__ ok, u16* __restrict__ ov) {
    __shared__ float tile[64][65];
    int z = blockIdx.z;
    bool isV = z >= 16;
    int b = isV ? z - 16 : z;
    const float* x = isV ? xv : xk;
    u16* out = isV ? ov : ok;
    int l0 = blockIdx.x * 64, i0 = blockIdx.y * 64;
    int t = threadIdx.x;
    const float* xb = x + (size_t)b * 1024 * 512;
    u16* ob = out + (size_t)b * 520 * 1024;
    if (blockIdx.x == 0 && t < 96) {   // zero pad rows 0..5, cols i0..i0+63
        int pr = t >> 4, pc = (t & 15) * 4;
        u16x4 zz = { 0, 0, 0, 0 };
        *(u16x4*)(ob + (size_t)pr * 1024 + i0 + pc) = zz;
    }
    int tr = t >> 4, tc = (t & 15) * 4;
#pragma unroll
    for (int r = 0; r < 4; ++r) {
        int row = tr + r * 16;
        float4 v = *(const float4*)(xb + (size_t)(i0 + row) * 512 + l0 + tc);
        tile[row][tc + 0] = v.x; tile[row][tc + 1] = v.y;
        tile[row][tc + 2] = v.z; tile[row][tc + 3] = v.w;
    }
    __syncthreads();
#pragma unroll
    for (int r = 0; r < 4; ++r) {
        int lr = tr + r * 16;
        u16x4 o = { f2bf(tile[tc + 0][lr]), f2bf(tile[tc + 1][lr]),
                    f2bf(tile[tc + 2][lr]), f2bf(tile[tc + 3][lr]) };
        *(u16x4*)(ob + (size_t)(l0 + 6 + lr) * 1024 + i0 + tc) = o;
    }
}

// ---------------- dual-conv GEMM, 128x256 tile, 2 blocks/CU, tap-reuse ----------------
// (r13 kernel VERBATIM: known-pass, conv ~200us, MfmaUtil 53%, conflicts 0.
//  r14 lesson: A must stay in LDS — per-tap A-from-L2 global loads put VMEM
//  latency on the MFMA critical path, 199->269us regression.)
__global__ __launch_bounds__(256, 2)
void k_conv128(const u16* __restrict__ WtK, const u16* __restrict__ WtV,
               const u16* __restrict__ XtK, const u16* __restrict__ XtV,
               const float* __restrict__ bK, const float* __restrict__ bV,
               u16* __restrict__ YK, u16* __restrict__ YV) {
    __shared__ __align__(16) u16 As[2][8192];    // 2 x [128][64]
    __shared__ __align__(16) u16 Bs[16896];      // [264][64]
    int id = blockIdx.x;
    int o0 = (id & 7) * 128;
    bool isV = (id >> 3) & 1;
    int inner = id >> 4;                 // 0..31
    int b = inner & 15;
    int l0 = (inner >> 4) * 256;
    const u16* Wt = isV ? WtV : WtK;
    const u16* Xb = (isV ? XtV : XtK) + (size_t)b * 520 * 1024;
    int tid = threadIdx.x, lane = tid & 63, wave = tid >> 6;
    int q = lane & 15, g = lane >> 4;
    int wm = wave >> 1, wn = wave & 1;

    int sr = tid >> 3;                   // 0..31
    int ss = (tid & 7) ^ (sr & 7);

    auto stageA = [&](int ic, int t, int slot) {
        const u16* a = Wt + ((size_t)t << 20) + (size_t)(o0 + sr) * 1024 + (ic << 6) + ss * 8;
        u16* ad = &As[slot][tid * 8];
#pragma unroll
        for (int l = 0; l < 4; ++l)
            gload16(a + (size_t)(l << 5) * 1024, ad + (l << 11));
    };
    auto stageB = [&](int ic) {
        const u16* bb = Xb + (size_t)(l0 + sr) * 1024 + (ic << 6) + ss * 8;
        u16* bd = &Bs[tid * 8];
#pragma unroll
        for (int l = 0; l < 8; ++l)
            gload16(bb + (size_t)(l << 5) * 1024, bd + (l << 11));
        int sr5 = 256 + (sr & 7);        // sr5&7 == sr&7 -> same ss key
        gload16(Xb + (size_t)(l0 + sr5) * 1024 + (ic << 6) + ss * 8,
                &Bs[sr5 * 64 + (tid & 7) * 8]);
    };

    f32x4 acc[4][8] = {};

    stageB(0);
    stageA(0, 0, 0);
    stageA(0, 1, 1);
    asm volatile("s_waitcnt vmcnt(4)" ::: "memory");  // B0 + A(0,0) landed
    __builtin_amdgcn_s_barrier();

    int ic2 = 0, t2 = 2;  // rolling index of A(s+2)
    for (int ic = 0; ic < 16; ++ic) {
        for (int t = 0; t < 7; ++t) {
            int s = ic * 7 + t;
            const u16* Asl = As[s & 1];
            bf16x8 af[4][2], bfr[4][2];

            // cluster 1: af (8 reads) + bfr nf 0..3 (8 reads); 32 MFMA
#pragma unroll
            for (int mf = 0; mf < 4; ++mf) {
                int r = wm * 64 + mf * 16 + q;
                const u16* base = Asl + r * 64;
#pragma unroll
                for (int kk = 0; kk < 2; ++kk)
                    af[mf][kk] = *(const bf16x8*)(base + (((kk * 4 + g) ^ (r & 7)) << 3));
            }
#pragma unroll
            for (int nf = 0; nf < 4; ++nf) {
                int r = wn * 128 + nf * 16 + q + t;
                const u16* base = Bs + r * 64;
#pragma unroll
                for (int kk = 0; kk < 2; ++kk)
                    bfr[nf][kk] = *(const bf16x8*)(base + (((kk * 4 + g) ^ (r & 7)) << 3));
            }
#pragma unroll
            for (int mf = 0; mf < 4; ++mf)
#pragma unroll
                for (int nf = 0; nf < 4; ++nf)
#pragma unroll
                    for (int kk = 0; kk < 2; ++kk)
                        acc[mf][nf] = __builtin_amdgcn_mfma_f32_16x16x32_bf16(
                            af[mf][kk], bfr[nf][kk], acc[mf][nf], 0, 0, 0);

            // cluster 2: bfr nf 4..7 (8 reads, reuse regs); 32 MFMA
#pragma unroll
            for (int nf = 0; nf < 4; ++nf) {
                int r = wn * 128 + (4 + nf) * 16 + q + t;
                const u16* base = Bs + r * 64;
#pragma unroll
                for (int kk = 0; kk < 2; ++kk)
                    bfr[nf][kk] = *(const bf16x8*)(base + (((kk * 4 + g) ^ (r & 7)) << 3));
            }
#pragma unroll
            for (int mf = 0; mf < 4; ++mf)
#pragma unroll
                for (int nf = 0; nf < 4; ++nf)
#pragma unroll
                    for (int kk = 0; kk < 2; ++kk)
                        acc[mf][4 + nf] = __builtin_amdgcn_mfma_f32_16x16x32_bf16(
                            af[mf][kk], bfr[nf][kk], acc[mf][4 + nf], 0, 0, 0);

            asm volatile("" ::: "memory");
            __builtin_amdgcn_s_barrier();        // all reads of A slot / B slab retired
            if (s + 2 < 112) {
                if (t == 6) stageB(ic + 1);      // safe: B reads done; issued BEFORE A
                stageA(ic2, t2, s & 1);          // A(s+2) into just-drained slot
                if (++t2 == 7) { t2 = 0; ++ic2; }
                asm volatile("s_waitcnt vmcnt(4)" ::: "memory");  // A(s+1) [+B] landed
            } else {
                asm volatile("s_waitcnt vmcnt(0)" ::: "memory");
            }
            __builtin_amdgcn_s_barrier();        // staged data visible to all
        }
    }

    const float* bias = isV ? bV : bK;
#pragma unroll
    for (int mf = 0; mf < 4; ++mf) {
        int ro = o0 + wm * 64 + mf * 16 + g * 4;
        float b0 = bias[ro + 0], b1 = bias[ro + 1], b2 = bias[ro + 2], b3 = bias[ro + 3];
#pragma unroll
        for (int nf = 0; nf < 8; ++nf) {
            int co = l0 + wn * 128 + nf * 16 + q;
            f32x4 a = acc[mf][nf];
            if (isV) {
                u16x4 o = { f2bf(a[0] + b0), f2bf(a[1] + b1), f2bf(a[2] + b2), f2bf(a[3] + b3) };
                *(u16x4*)&YV[((size_t)b * 512 + co) * 1024 + ro] = o;
            } else {
                u16* yp = &YK[((size_t)b * 1024 + ro) * 512 + co];
                yp[0]    = f2bf(a[0] + b0);
                yp[512]  = f2bf(a[1] + b1);
                yp[1024] = f2bf(a[2] + b2);
                yp[1536] = f2bf(a[3] + b3);
            }
        }
    }
}

// ---------------- fused attention (unchanged) ----------------
__global__ __launch_bounds__(512, 4)
void k_attn2(const u16* __restrict__ Q, const u16* __restrict__ K,
             const u16* __restrict__ Vt, u16* __restrict__ O) {
    __shared__ __align__(16) u16 Ks[2][64 * 64];
    __shared__ __align__(16) u16 Vs[2][64 * 64];
    int b = blockIdx.z, h = blockIdx.y, q0 = blockIdx.x * 128;
    int tid = threadIdx.x, lane = tid & 63, wave = tid >> 6;
    int g = lane >> 4, q = lane & 15;

    const u16* Kb = K + (size_t)b * 1024 * 512 + h * 64;
    const u16* Vb = Vt + ((size_t)b * 512 + h * 64) * 1024;
    const u16* Qb = Q + ((size_t)b * 1024 + q0 + wave * 16 + q) * 512 + h * 64;

    bf16x8 qf[2];
    qf[0] = *(const bf16x8*)(Qb + g * 8);
    qf[1] = *(const bf16x8*)(Qb + 32 + g * 8);

    int sr = tid >> 3;
    int ss = (tid & 7) ^ (sr & 7);
    const u16* ksrc = Kb + (size_t)sr * 512 + ss * 8;
    const u16* vsrc = Vb + (size_t)sr * 1024 + ss * 8;

    f32x4 o[4] = {};
    float lsum = 0.f;

    gload16(ksrc, &Ks[0][tid * 8]);
    gload16(vsrc, &Vs[0][tid * 8]);
    __syncthreads();

#pragma unroll 2
    for (int t = 0; t < 16; ++t) {
        int buf = t & 1;
        if (t < 15) {
            gload16(ksrc + (size_t)(t + 1) * 64 * 512, &Ks[buf ^ 1][tid * 8]);
            gload16(vsrc + (t + 1) * 64, &Vs[buf ^ 1][tid * 8]);
        }
        f32x4 s[4];
#pragma unroll
        for (int mf = 0; mf < 4; ++mf) {
            int r = 16 * mf + q;
            const u16* base = &Ks[buf][r * 64];
            bf16x8 kf0 = *(const bf16x8*)(base + (((g) ^ (q & 7)) << 3));
            bf16x8 kf1 = *(const bf16x8*)(base + (((4 + g) ^ (q & 7)) << 3));
            f32x4 zz = {};
            zz = __builtin_amdgcn_mfma_f32_16x16x32_bf16(kf0, qf[0], zz, 0, 0, 0);
            s[mf] = __builtin_amdgcn_mfma_f32_16x16x32_bf16(kf1, qf[1], zz, 0, 0, 0);
        }
        unsigned w[4][2];
#pragma unroll
        for (int mf = 0; mf < 4; ++mf) {
            f32x4 p;
#pragma unroll
            for (int j = 0; j < 4; ++j) {
                p[j] = exp2f(s[mf][j]);
                lsum += p[j];
            }
            w[mf][0] = cvt_pk_bf16(p[0], p[1]);
            w[mf][1] = cvt_pk_bf16(p[2], p[3]);
        }
        bool hi = lane >= 32;
        int ia = ((g & 1) << 5) + q;
        int ib = ia + 16;
#pragma unroll
        for (int c = 0; c < 2; ++c) {
            unsigned a0 = __shfl(w[2 * c][0], ia), b0 = __shfl(w[2 * c + 1][0], ia);
            unsigned a1 = __shfl(w[2 * c][1], ia), b1 = __shfl(w[2 * c + 1][1], ia);
            unsigned a2 = __shfl(w[2 * c][0], ib), b2 = __shfl(w[2 * c + 1][0], ib);
            unsigned a3 = __shfl(w[2 * c][1], ib), b3 = __shfl(w[2 * c + 1][1], ib);
            union { unsigned u[4]; bf16x8 v8; } pu;
            pu.u[0] = hi ? b0 : a0;
            pu.u[1] = hi ? b1 : a1;
            pu.u[2] = hi ? b2 : a2;
            pu.u[3] = hi ? b3 : a3;
            bf16x8 pb = pu.v8;
#pragma unroll
            for (int df = 0; df < 4; ++df) {
                int rd = 16 * df + q;
                bf16x8 vf = *(const bf16x8*)(&Vs[buf][rd * 64] + (((c * 4 + g) ^ (q & 7)) << 3));
                o[df] = __builtin_amdgcn_mfma_f32_16x16x32_bf16(vf, pb, o[df], 0, 0, 0);
            }
        }
        __syncthreads();
    }

    lsum += __shfl_xor(lsum, 16);
    lsum += __shfl_xor(lsum, 32);
    float inv = 1.0f / lsum;

    unsigned wo[4][2];
#pragma unroll
    for (int df = 0; df < 4; ++df) {
        f32x4 v = o[df];
        v[0] *= inv; v[1] *= inv; v[2] *= inv; v[3] *= inv;
        wo[df][0] = cvt_pk_bf16(v[0], v[1]);
        wo[df][1] = cvt_pk_bf16(v[2], v[3]);
    }
    bool hi = lane >= 32;
    int ia = ((g & 1) << 5) + q;
    int ib = ia + 16;
    u16* Ob = O + ((size_t)b * 1024 + q0 + wave * 16 + q) * 512 + h * 64;
#pragma unroll
    for (int c = 0; c < 2; ++c) {
        unsigned a0 = __shfl(wo[2 * c][0], ia), b0 = __shfl(wo[2 * c + 1][0], ia);
        unsigned a1 = __shfl(wo[2 * c][1], ia), b1 = __shfl(wo[2 * c + 1][1], ia);
        unsigned a2 = __shfl(wo[2 * c][0], ib), b2 = __shfl(wo[2 * c + 1][0], ib);
        unsigned a3 = __shfl(wo[2 * c][1], ib), b3 = __shfl(wo[2 * c + 1][1], ib);
        int4 st;
        st.x = (int)(hi ? b0 : a0);
        st.y = (int)(hi ? b1 : a1);
        st.z = (int)(hi ? b2 : a2);
        st.w = (int)(hi ? b3 : a3);
        *(int4*)(Ob + c * 32 + g * 8) = st;
    }
}

// ---------------- output linear ----------------
__global__ __launch_bounds__(256, 2)
void k_gemm_out(const u16* __restrict__ A, const u16* __restrict__ Bt,
                const float* __restrict__ bias, float* __restrict__ C) {
    __shared__ __align__(16) u16 As[128 * 64];
    __shared__ __align__(16) u16 Bs[128 * 64];
    int n0 = blockIdx.x * 128, m0 = blockIdx.y * 128;
    int tid = threadIdx.x, lane = tid & 63, wave = tid >> 6;
    int wr = (wave >> 1) * 64, wc = (wave & 1) * 64;
    f32x4 acc[4][4] = {};

    for (int kk = 0; kk < 8; ++kk) {
        int i0 = kk * 64;
        const u16* asrc = A + (size_t)(m0 + (tid >> 3)) * 512 + i0 + (tid & 7) * 8;
        const u16* bsrc = Bt + (size_t)(n0 + (tid >> 3)) * 512 + i0 + (tid & 7) * 8;
        __syncthreads();
#pragma unroll
        for (int s = 0; s < 4; ++s) {
            gload16(asrc + (size_t)s * 32 * 512, &As[s * 2048 + tid * 8]);
            gload16(bsrc + (size_t)s * 32 * 512, &Bs[s * 2048 + tid * 8]);
        }
        __syncthreads();
#pragma unroll
        for (int ks = 0; ks < 2; ++ks) {
            bf16x8 af[4], bfr[4];
#pragma unroll
            for (int m = 0; m < 4; ++m)
                af[m] = *(const bf16x8*)&As[(wr + m * 16 + (lane & 15)) * 64 + ks * 32 + (lane >> 4) * 8];
#pragma unroll
            for (int n = 0; n < 4; ++n)
                bfr[n] = *(const bf16x8*)&Bs[(wc + n * 16 + (lane & 15)) * 64 + ks * 32 + (lane >> 4) * 8];
#pragma unroll
            for (int m = 0; m < 4; ++m)
#pragma unroll
                for (int n = 0; n < 4; ++n)
                    acc[m][n] = __builtin_amdgcn_mfma_f32_16x16x32_bf16(af[m], bfr[n], acc[m][n], 0, 0, 0);
        }
    }

#pragma unroll
    for (int m = 0; m < 4; ++m) {
        int ro = m0 + wr + m * 16 + (lane >> 4) * 4;
#pragma unroll
        for (int n = 0; n < 4; ++n) {
            int co = n0 + wc + n * 16 + (lane & 15);
            float bb = bias[co];
            float* cp = &C[(size_t)ro * 512 + co];
            cp[0]    = acc[m][n][0] + bb;
            cp[512]  = acc[m][n][1] + bb;
            cp[1024] = acc[m][n][2] + bb;
            cp[1536] = acc[m][n][3] + bb;
        }
    }
}

// ---------------- launcher ----------------
extern "C" void kernel_launch(void* const* d_in, const int* in_sizes, int n_in,
                              void* d_out, int out_size, void* d_ws, size_t ws_size,
                              hipStream_t stream) {
    (void)in_sizes; (void)n_in; (void)out_size; (void)ws_size;
    const float* query = (const float*)d_in[0];
    const float* key   = (const float*)d_in[1];
    const float* value = (const float*)d_in[2];
    const float* wk    = (const float*)d_in[3];
    const float* bk    = (const float*)d_in[4];
    const float* wv    = (const float*)d_in[5];
    const float* bv    = (const float*)d_in[6];
    const float* lw    = (const float*)d_in[7];
    const float* lb    = (const float*)d_in[8];
    float* out = (float*)d_out;

    u16* ws16  = (u16*)d_ws;
    u16* q_bf  = ws16;                  // [16][1024][512]  q * (1/8)*log2e
    u16* k_att = q_bf  + 8388608;       // [16][1024][512]  conv-K out
    u16* v_t   = k_att + 8388608;       // [16][512][1024]  conv-V out (transposed)
    u16* x_att = v_t   + 8388608;       // [16][1024][512]  attention out
    u16* xt_k  = x_att + 8388608;       // [16][520][1024]  key transposed+padded
    u16* xt_v  = xt_k  + 8519680;       // [16][520][1024]
    u16* wk_bf = xt_v  + 8519680;       // [7][1024][1024]
    u16* wv_bf = wk_bf + 7340032;       // [7][1024][1024]
    u16* lw_bf = wv_bf + 7340032;       // [512][512]

    k_cast_both<<<8448, 256, 0, stream>>>(query, q_bf, lw, lw_bf);
    k_castW2<<<dim3(4096, 2), 256, 0, stream>>>(wk, wv, wk_bf, wv_bf);
    k_transpose_pad2<<<dim3(8, 16, 32), 256, 0, stream>>>(key, value, xt_k, xt_v);

    k_conv128<<<dim3(512, 1, 1), 256, 0, stream>>>(wk_bf, wv_bf, xt_k, xt_v, bk, bv, k_att, v_t);

    k_attn2<<<dim3(8, 8, 16), 512, 0, stream>>>(q_bf, k_att, v_t, x_att);

    k_gemm_out<<<dim3(4, 128), 256, 0, stream>>>(x_att, lw_bf, lb, out);
}